// Round 1
// baseline (818.815 us; speedup 1.0000x reference)
//
#include <hip/hip_runtime.h>
#include <hip/hip_bf16.h>

#define N_NODES 20000
#define N_EDGES 320000
#define N_ADJ   4
#define D       256
#define RP      (N_NODES + 1)   // row_ptr stride per adjacency

// ---------------------------------------------------------------------------
// CSR build: histogram -> exclusive scan -> scatter
// ---------------------------------------------------------------------------

__global__ __launch_bounds__(256) void hist_kernel(const int* __restrict__ rows,
                                                   int* __restrict__ cnt) {
    int e = blockIdx.x * 256 + threadIdx.x;
    int a = blockIdx.y;
    if (e < N_EDGES) {
        atomicAdd(&cnt[a * N_NODES + rows[a * N_EDGES + e]], 1);
    }
}

__global__ __launch_bounds__(256) void scan_kernel(const int* __restrict__ cnt,
                                                   int* __restrict__ row_ptr,
                                                   int* __restrict__ work) {
    int a = blockIdx.x;
    int t = threadIdx.x;
    __shared__ int buf[256];
    int carry = 0;
    for (int base = 0; base < N_NODES; base += 256) {
        int i = base + t;
        int v = (i < N_NODES) ? cnt[a * N_NODES + i] : 0;
        buf[t] = v;
        __syncthreads();
        #pragma unroll
        for (int off = 1; off < 256; off <<= 1) {
            int add = (t >= off) ? buf[t - off] : 0;
            __syncthreads();
            buf[t] += add;
            __syncthreads();
        }
        int incl  = buf[t];
        int total = buf[255];
        __syncthreads();  // protect buf before next iteration's overwrite
        if (i < N_NODES) {
            int val = carry + incl - v;   // exclusive
            row_ptr[a * RP + i]    = val;
            work[a * N_NODES + i]  = val;
        }
        carry += total;
    }
    if (t == 0) row_ptr[a * RP + N_NODES] = carry;
}

__global__ __launch_bounds__(256) void scatter_kernel(const int* __restrict__ rows,
                                                      const int* __restrict__ cols,
                                                      const float* __restrict__ vals,
                                                      int* __restrict__ work,
                                                      int2* __restrict__ csr) {
    int e = blockIdx.x * 256 + threadIdx.x;
    int a = blockIdx.y;
    if (e < N_EDGES) {
        int r = rows[a * N_EDGES + e];
        int idx = atomicAdd(&work[a * N_NODES + r], 1);
        csr[a * N_EDGES + idx] =
            make_int2(cols[a * N_EDGES + e], __float_as_int(vals[a * N_EDGES + e]));
    }
}

// ---------------------------------------------------------------------------
// Dense affine: h = x @ W + b.  Block = 256 threads (thread t = out column),
// 16 rows per block; x values are wave-uniform -> scalar loads.
// ---------------------------------------------------------------------------

__global__ __launch_bounds__(256) void matmul_kernel(const float* __restrict__ x,
                                                     const float* __restrict__ W,
                                                     const float* __restrict__ b,
                                                     float* __restrict__ h) {
    int t  = threadIdx.x;
    int r0 = blockIdx.x * 16;
    const float* xr = x + (long)r0 * D;
    float acc[16];
    #pragma unroll
    for (int r = 0; r < 16; ++r) acc[r] = 0.f;
    for (int k = 0; k < D; ++k) {
        float w = W[k * D + t];
        #pragma unroll
        for (int r = 0; r < 16; ++r) acc[r] += xr[r * D + k] * w;
    }
    float bb = b[t];
    #pragma unroll
    for (int r = 0; r < 16; ++r) h[(long)(r0 + r) * D + t] = acc[r] + bb;
}

// ---------------------------------------------------------------------------
// Per-row gather over one adjacency's CSR segment; unrolled x4 for MLP
// (memory-level parallelism).  All control flow is wave-uniform.
// ---------------------------------------------------------------------------

__device__ __forceinline__ float gather_row(const int2* __restrict__ E,
                                            int beg, int end,
                                            const float* __restrict__ feat, int t) {
    float s = 0.f;
    int e = beg;
    for (; e + 4 <= end; e += 4) {
        int2 c0 = E[e], c1 = E[e + 1], c2 = E[e + 2], c3 = E[e + 3];
        float h0 = feat[(c0.x << 8) + t];
        float h1 = feat[(c1.x << 8) + t];
        float h2 = feat[(c2.x << 8) + t];
        float h3 = feat[(c3.x << 8) + t];
        s += __int_as_float(c0.y) * h0;
        s += __int_as_float(c1.y) * h1;
        s += __int_as_float(c2.y) * h2;
        s += __int_as_float(c3.y) * h3;
    }
    for (; e < end; ++e) {
        int2 c = E[e];
        s += __int_as_float(c.y) * feat[(c.x << 8) + t];
    }
    return s;
}

// ---------------------------------------------------------------------------
// Stage 1: input h.  Emits s1, s2-partial, out-partial.
//   s1  = ( wseq0[0][a] * t_a(h), a=0..2 ) / 3
//   s2p = ( wres0[a]    * t_a(h), a=0..3 ) / 4
//   op  = ( wres1[0][j] * t_a(h), a in {0,1,3} ) / 3
// ---------------------------------------------------------------------------

__global__ __launch_bounds__(256) void stage1_kernel(const float* __restrict__ h,
                                                     const int* __restrict__ row_ptr,
                                                     const int2* __restrict__ csr,
                                                     const float* __restrict__ wseq0,
                                                     const float* __restrict__ wres0,
                                                     const float* __restrict__ wres1,
                                                     float* __restrict__ s1,
                                                     float* __restrict__ s2,
                                                     float* __restrict__ outp) {
    int r = blockIdx.x, t = threadIdx.x;
    float acc[N_ADJ];
    #pragma unroll
    for (int a = 0; a < N_ADJ; ++a) {
        int beg = row_ptr[a * RP + r];
        int end = row_ptr[a * RP + r + 1];
        acc[a] = gather_row(csr + a * N_EDGES, beg, end, h, t);
    }
    const float third = 1.f / 3.f;
    float s1v = (wseq0[0] * acc[0] + wseq0[1] * acc[1] + wseq0[2] * acc[2]) * third;
    float s2v = (wres0[0] * acc[0] + wres0[1] * acc[1] + wres0[2] * acc[2] +
                 wres0[3] * acc[3]) * 0.25f;
    float ov  = (wres1[0] * acc[0] + wres1[1] * acc[1] + wres1[2] * acc[3]) * third;
    int o = (r << 8) + t;
    s1[o]   = s1v;
    s2[o]   = s2v;
    outp[o] = ov;
}

// ---------------------------------------------------------------------------
// Stage 2: input s1.  s2 += seq-combo; out-partial += res-combo.
// ---------------------------------------------------------------------------

__global__ __launch_bounds__(256) void stage2_kernel(const float* __restrict__ s1,
                                                     const int* __restrict__ row_ptr,
                                                     const int2* __restrict__ csr,
                                                     const float* __restrict__ wseq0,
                                                     const float* __restrict__ wres1,
                                                     float* __restrict__ s2,
                                                     float* __restrict__ outp) {
    int r = blockIdx.x, t = threadIdx.x;
    float acc[N_ADJ];
    #pragma unroll
    for (int a = 0; a < N_ADJ; ++a) {
        int beg = row_ptr[a * RP + r];
        int end = row_ptr[a * RP + r + 1];
        acc[a] = gather_row(csr + a * N_EDGES, beg, end, s1, t);
    }
    const float third = 1.f / 3.f;
    int o = (r << 8) + t;
    s2[o]   += (wseq0[3] * acc[0] + wseq0[4] * acc[1] + wseq0[5] * acc[2]) * third;
    outp[o] += (wres1[3] * acc[0] + wres1[4] * acc[1] + wres1[5] * acc[3]) * third;
}

// ---------------------------------------------------------------------------
// Stage 3: input s2 (adjacencies 0,1 only), add out-partial, LayerNorm, GELU.
// ---------------------------------------------------------------------------

__global__ __launch_bounds__(256) void stage3_kernel(const float* __restrict__ s2,
                                                     const int* __restrict__ row_ptr,
                                                     const int2* __restrict__ csr,
                                                     const float* __restrict__ wseq1,
                                                     const float* __restrict__ outp,
                                                     float* __restrict__ out) {
    int r = blockIdx.x, t = threadIdx.x;
    float acc[2];
    #pragma unroll
    for (int a = 0; a < 2; ++a) {
        int beg = row_ptr[a * RP + r];
        int end = row_ptr[a * RP + r + 1];
        acc[a] = gather_row(csr + a * N_EDGES, beg, end, s2, t);
    }
    int o = (r << 8) + t;
    float val = outp[o] + (wseq1[0] * acc[0] + wseq1[1] * acc[1]) * 0.5f;

    // block LayerNorm reduction over 256 features
    float v = val, v2 = val * val;
    #pragma unroll
    for (int off = 32; off > 0; off >>= 1) {
        v  += __shfl_down(v, off, 64);
        v2 += __shfl_down(v2, off, 64);
    }
    __shared__ float sred[8];
    int wid = t >> 6, lane = t & 63;
    if (lane == 0) { sred[wid] = v; sred[4 + wid] = v2; }
    __syncthreads();
    float sum  = sred[0] + sred[1] + sred[2] + sred[3];
    float sum2 = sred[4] + sred[5] + sred[6] + sred[7];
    float mu   = sum * (1.f / 256.f);
    float var  = sum2 * (1.f / 256.f) - mu * mu;
    float rstd = rsqrtf(var + 1e-5f);
    float y    = (val - mu) * rstd;
    out[o] = 0.5f * y * (1.f + erff(y * 0.70710678118654752440f));
}

// ---------------------------------------------------------------------------

extern "C" void kernel_launch(void* const* d_in, const int* in_sizes, int n_in,
                              void* d_out, int out_size, void* d_ws, size_t ws_size,
                              hipStream_t stream) {
    const float* x     = (const float*)d_in[0];
    const int*   rows  = (const int*)d_in[1];
    const int*   cols  = (const int*)d_in[2];
    const float* vals  = (const float*)d_in[3];
    const float* W     = (const float*)d_in[4];
    const float* b     = (const float*)d_in[5];
    const float* wseq0 = (const float*)d_in[6];  // (2,3)
    const float* wseq1 = (const float*)d_in[7];  // (2,)
    const float* wres0 = (const float*)d_in[8];  // (1,4)
    const float* wres1 = (const float*)d_in[9];  // (2,3)
    float* out = (float*)d_out;

    char* p = (char*)d_ws;
    float* h       = (float*)p; p += (size_t)N_NODES * D * 4;        // 20.48 MB
    float* s1      = (float*)p; p += (size_t)N_NODES * D * 4;        // 20.48 MB
    float* s2      = (float*)p; p += (size_t)N_NODES * D * 4;        // 20.48 MB
    int*   row_ptr = (int*)p;   p += 320032;                          // 4*RP ints, padded
    int*   cnt     = (int*)p;   p += (size_t)N_ADJ * N_NODES * 4;    // 320 KB
    int*   work    = (int*)p;   p += (size_t)N_ADJ * N_NODES * 4;    // 320 KB
    int2*  csr     = (int2*)p;                                        // 10.24 MB

    hipMemsetAsync(cnt, 0, (size_t)N_ADJ * N_NODES * sizeof(int), stream);

    dim3 egrid((N_EDGES + 255) / 256, N_ADJ);
    hist_kernel<<<egrid, 256, 0, stream>>>(rows, cnt);
    scan_kernel<<<N_ADJ, 256, 0, stream>>>(cnt, row_ptr, work);
    scatter_kernel<<<egrid, 256, 0, stream>>>(rows, cols, vals, work, csr);

    matmul_kernel<<<N_NODES / 16, 256, 0, stream>>>(x, W, b, h);

    stage1_kernel<<<N_NODES, 256, 0, stream>>>(h, row_ptr, csr, wseq0, wres0, wres1,
                                               s1, s2, out);
    stage2_kernel<<<N_NODES, 256, 0, stream>>>(s1, row_ptr, csr, wseq0, wres1,
                                               s2, out);
    stage3_kernel<<<N_NODES, 256, 0, stream>>>(s2, row_ptr, csr, wseq1, out, out);
}

// Round 2
// 604.143 us; speedup vs baseline: 1.3553x; 1.3553x over previous
//
#include <hip/hip_runtime.h>
#include <hip/hip_bf16.h>

#define N_NODES 20000
#define N_EDGES 320000
#define N_ADJ   4
#define D       256
#define DH      128              // packed bf16x2 dwords per feature row
#define RP      (N_NODES + 1)    // row_ptr stride per adjacency

// ---------------------------------------------------------------------------
// bf16 pack/unpack helpers (RNE rounding; values are finite)
// ---------------------------------------------------------------------------

__device__ __forceinline__ unsigned f2bf_bits(float x) {
    unsigned u = __float_as_uint(x);
    return (u + 0x7FFFu + ((u >> 16) & 1u)) >> 16;
}
__device__ __forceinline__ unsigned pack_bf2(float lo, float hi) {
    return f2bf_bits(lo) | (f2bf_bits(hi) << 16);
}
__device__ __forceinline__ float bf_lo(unsigned p) { return __uint_as_float(p << 16); }
__device__ __forceinline__ float bf_hi(unsigned p) { return __uint_as_float(p & 0xFFFF0000u); }

// ---------------------------------------------------------------------------
// CSR build: histogram -> exclusive scan -> scatter
// ---------------------------------------------------------------------------

__global__ __launch_bounds__(256) void hist_kernel(const int* __restrict__ rows,
                                                   int* __restrict__ cnt) {
    int e = blockIdx.x * 256 + threadIdx.x;
    int a = blockIdx.y;
    if (e < N_EDGES) {
        atomicAdd(&cnt[a * N_NODES + rows[a * N_EDGES + e]], 1);
    }
}

// 1024 threads, shuffle-based wave scans; 2 barriers per 1024-chunk.
__global__ __launch_bounds__(1024) void scan_kernel(const int* __restrict__ cnt,
                                                    int* __restrict__ row_ptr,
                                                    int* __restrict__ work) {
    int a = blockIdx.x, t = threadIdx.x;
    int lane = t & 63, w = t >> 6;            // 16 waves
    __shared__ int wsum[16];
    int carry = 0;
    for (int base = 0; base < N_NODES; base += 1024) {
        int i = base + t;
        int v = (i < N_NODES) ? cnt[a * N_NODES + i] : 0;
        int s = v;                            // inclusive wave scan
        #pragma unroll
        for (int off = 1; off < 64; off <<= 1) {
            int u = __shfl_up(s, off, 64);
            if (lane >= off) s += u;
        }
        if (lane == 63) wsum[w] = s;
        __syncthreads();
        int woff = 0, total = 0;
        #pragma unroll
        for (int j = 0; j < 16; ++j) {        // LDS broadcast reads, no conflicts
            int ws = wsum[j];
            woff  += (j < w) ? ws : 0;
            total += ws;
        }
        __syncthreads();                      // protect wsum before next chunk
        if (i < N_NODES) {
            int val = carry + woff + s - v;   // exclusive
            row_ptr[a * RP + i]   = val;
            work[a * N_NODES + i] = val;
        }
        carry += total;
    }
    if (t == 0) row_ptr[a * RP + N_NODES] = carry;
}

__global__ __launch_bounds__(256) void scatter_kernel(const int* __restrict__ rows,
                                                      const int* __restrict__ cols,
                                                      const float* __restrict__ vals,
                                                      int* __restrict__ work,
                                                      int2* __restrict__ csr) {
    int e = blockIdx.x * 256 + threadIdx.x;
    int a = blockIdx.y;
    if (e < N_EDGES) {
        int r = rows[a * N_EDGES + e];
        int idx = atomicAdd(&work[a * N_NODES + r], 1);
        csr[(size_t)a * N_EDGES + idx] =
            make_int2(cols[a * N_EDGES + e], __float_as_int(vals[a * N_EDGES + e]));
    }
}

// ---------------------------------------------------------------------------
// Dense affine: h = x @ W + b, output packed bf16x2.  Thread t = feature t;
// even lanes pack (feat 2j, 2j+1) via shfl and store one dword.
// ---------------------------------------------------------------------------

__global__ __launch_bounds__(256) void matmul_kernel(const float* __restrict__ x,
                                                     const float* __restrict__ W,
                                                     const float* __restrict__ b,
                                                     unsigned* __restrict__ hp) {
    int t  = threadIdx.x;
    int r0 = blockIdx.x * 16;
    const float* xr = x + (long)r0 * D;
    float acc[16];
    #pragma unroll
    for (int r = 0; r < 16; ++r) acc[r] = 0.f;
    for (int k = 0; k < D; ++k) {
        float w = W[k * D + t];
        #pragma unroll
        for (int r = 0; r < 16; ++r) acc[r] += xr[r * D + k] * w;
    }
    float bb = b[t];
    #pragma unroll
    for (int r = 0; r < 16; ++r) {
        float v = acc[r] + bb;
        float other = __shfl_xor(v, 1, 64);   // partner feature
        if ((t & 1) == 0) {
            hp[(r0 + r) * DH + (t >> 1)] = pack_bf2(v, other);
        }
    }
}

// ---------------------------------------------------------------------------
// Gather one row's segment of one adjacency from a packed-bf16 feature table.
// Thread tt in [0,128) owns features (2tt, 2tt+1).  Unrolled x4 for MLP.
// ---------------------------------------------------------------------------

__device__ __forceinline__ void gather_row2(const int2* __restrict__ E,
                                            int beg, int end,
                                            const unsigned* __restrict__ feat,
                                            int tt, float& r0, float& r1) {
    float s0 = 0.f, s1 = 0.f;
    int e = beg;
    for (; e + 4 <= end; e += 4) {
        int2 c0 = E[e], c1 = E[e + 1], c2 = E[e + 2], c3 = E[e + 3];
        unsigned p0 = feat[c0.x * DH + tt];
        unsigned p1 = feat[c1.x * DH + tt];
        unsigned p2 = feat[c2.x * DH + tt];
        unsigned p3 = feat[c3.x * DH + tt];
        float v0 = __int_as_float(c0.y), v1 = __int_as_float(c1.y);
        float v2 = __int_as_float(c2.y), v3 = __int_as_float(c3.y);
        s0 += v0 * bf_lo(p0); s1 += v0 * bf_hi(p0);
        s0 += v1 * bf_lo(p1); s1 += v1 * bf_hi(p1);
        s0 += v2 * bf_lo(p2); s1 += v2 * bf_hi(p2);
        s0 += v3 * bf_lo(p3); s1 += v3 * bf_hi(p3);
    }
    for (; e < end; ++e) {
        int2 c = E[e];
        unsigned p = feat[c.x * DH + tt];
        float v = __int_as_float(c.y);
        s0 += v * bf_lo(p); s1 += v * bf_hi(p);
    }
    r0 = s0; r1 = s1;
}

// ---------------------------------------------------------------------------
// Stage 1: input h (packed).  Emits s1, s2-partial (packed) and out-partial
// (f32, into d_out).  2 rows per block; waves 0-1 -> row 2b, waves 2-3 -> 2b+1.
// ---------------------------------------------------------------------------

__global__ __launch_bounds__(256) void stage1_kernel(const unsigned* __restrict__ hp,
                                                     const int* __restrict__ row_ptr,
                                                     const int2* __restrict__ csr,
                                                     const float* __restrict__ wseq0,
                                                     const float* __restrict__ wres0,
                                                     const float* __restrict__ wres1,
                                                     unsigned* __restrict__ s1p,
                                                     unsigned* __restrict__ s2p,
                                                     float2* __restrict__ outp) {
    int t = threadIdx.x, tt = t & 127;
    int r = blockIdx.x * 2 + (t >> 7);
    float a0[N_ADJ], a1[N_ADJ];
    #pragma unroll
    for (int a = 0; a < N_ADJ; ++a) {
        int beg = row_ptr[a * RP + r];
        int end = row_ptr[a * RP + r + 1];
        gather_row2(csr + (size_t)a * N_EDGES, beg, end, hp, tt, a0[a], a1[a]);
    }
    const float third = 1.f / 3.f;
    float s1v0 = (wseq0[0] * a0[0] + wseq0[1] * a0[1] + wseq0[2] * a0[2]) * third;
    float s1v1 = (wseq0[0] * a1[0] + wseq0[1] * a1[1] + wseq0[2] * a1[2]) * third;
    float s2v0 = (wres0[0] * a0[0] + wres0[1] * a0[1] + wres0[2] * a0[2] + wres0[3] * a0[3]) * 0.25f;
    float s2v1 = (wres0[0] * a1[0] + wres0[1] * a1[1] + wres0[2] * a1[2] + wres0[3] * a1[3]) * 0.25f;
    float ov0  = (wres1[0] * a0[0] + wres1[1] * a0[1] + wres1[2] * a0[3]) * third;
    float ov1  = (wres1[0] * a1[0] + wres1[1] * a1[1] + wres1[2] * a1[3]) * third;
    int o = r * DH + tt;
    s1p[o]  = pack_bf2(s1v0, s1v1);
    s2p[o]  = pack_bf2(s2v0, s2v1);
    outp[o] = make_float2(ov0, ov1);
}

// ---------------------------------------------------------------------------
// Stage 2: input s1 (packed).  s2 += seq-combo; out-partial += res-combo.
// ---------------------------------------------------------------------------

__global__ __launch_bounds__(256) void stage2_kernel(const unsigned* __restrict__ s1p,
                                                     const int* __restrict__ row_ptr,
                                                     const int2* __restrict__ csr,
                                                     const float* __restrict__ wseq0,
                                                     const float* __restrict__ wres1,
                                                     unsigned* __restrict__ s2p,
                                                     float2* __restrict__ outp) {
    int t = threadIdx.x, tt = t & 127;
    int r = blockIdx.x * 2 + (t >> 7);
    float a0[N_ADJ], a1[N_ADJ];
    #pragma unroll
    for (int a = 0; a < N_ADJ; ++a) {
        int beg = row_ptr[a * RP + r];
        int end = row_ptr[a * RP + r + 1];
        gather_row2(csr + (size_t)a * N_EDGES, beg, end, s1p, tt, a0[a], a1[a]);
    }
    const float third = 1.f / 3.f;
    int o = r * DH + tt;
    unsigned sp = s2p[o];
    float c0 = bf_lo(sp) + (wseq0[3] * a0[0] + wseq0[4] * a0[1] + wseq0[5] * a0[2]) * third;
    float c1 = bf_hi(sp) + (wseq0[3] * a1[0] + wseq0[4] * a1[1] + wseq0[5] * a1[2]) * third;
    s2p[o] = pack_bf2(c0, c1);
    float2 op = outp[o];
    op.x += (wres1[3] * a0[0] + wres1[4] * a0[1] + wres1[5] * a0[3]) * third;
    op.y += (wres1[3] * a1[0] + wres1[4] * a1[1] + wres1[5] * a1[3]) * third;
    outp[o] = op;
}

// ---------------------------------------------------------------------------
// Stage 3: input s2 (adjacencies 0,1), add out-partial, LayerNorm, exact GELU.
// Per-row reduction runs over the row's 2 waves only.
// ---------------------------------------------------------------------------

__global__ __launch_bounds__(256) void stage3_kernel(const unsigned* __restrict__ s2p,
                                                     const int* __restrict__ row_ptr,
                                                     const int2* __restrict__ csr,
                                                     const float* __restrict__ wseq1,
                                                     float2* __restrict__ outp) {
    int t = threadIdx.x, tt = t & 127, half = t >> 7;
    int r = blockIdx.x * 2 + half;
    float a0[2], a1[2];
    #pragma unroll
    for (int a = 0; a < 2; ++a) {
        int beg = row_ptr[a * RP + r];
        int end = row_ptr[a * RP + r + 1];
        gather_row2(csr + (size_t)a * N_EDGES, beg, end, s2p, tt, a0[a], a1[a]);
    }
    int o = r * DH + tt;
    float2 op = outp[o];
    float val0 = op.x + (wseq1[0] * a0[0] + wseq1[1] * a0[1]) * 0.5f;
    float val1 = op.y + (wseq1[0] * a1[0] + wseq1[1] * a1[1]) * 0.5f;

    // LayerNorm over 256 features = 2 values x 128 threads (2 waves per row)
    float v = val0 + val1, v2 = val0 * val0 + val1 * val1;
    #pragma unroll
    for (int off = 32; off > 0; off >>= 1) {
        v  += __shfl_down(v, off, 64);
        v2 += __shfl_down(v2, off, 64);
    }
    __shared__ float sA[4], sB[4];
    int w = t >> 6, lane = t & 63;
    if (lane == 0) { sA[w] = v; sB[w] = v2; }
    __syncthreads();
    float sum  = sA[half * 2] + sA[half * 2 + 1];
    float sum2 = sB[half * 2] + sB[half * 2 + 1];
    float mu   = sum * (1.f / 256.f);
    float var  = sum2 * (1.f / 256.f) - mu * mu;
    float rstd = rsqrtf(var + 1e-5f);
    float y0   = (val0 - mu) * rstd;
    float y1   = (val1 - mu) * rstd;
    float g0 = 0.5f * y0 * (1.f + erff(y0 * 0.70710678118654752440f));
    float g1 = 0.5f * y1 * (1.f + erff(y1 * 0.70710678118654752440f));
    outp[o] = make_float2(g0, g1);
}

// ---------------------------------------------------------------------------

extern "C" void kernel_launch(void* const* d_in, const int* in_sizes, int n_in,
                              void* d_out, int out_size, void* d_ws, size_t ws_size,
                              hipStream_t stream) {
    const float* x     = (const float*)d_in[0];
    const int*   rows  = (const int*)d_in[1];
    const int*   cols  = (const int*)d_in[2];
    const float* vals  = (const float*)d_in[3];
    const float* W     = (const float*)d_in[4];
    const float* b     = (const float*)d_in[5];
    const float* wseq0 = (const float*)d_in[6];  // (2,3)
    const float* wseq1 = (const float*)d_in[7];  // (2,)
    const float* wres0 = (const float*)d_in[8];  // (1,4)
    const float* wres1 = (const float*)d_in[9];  // (2,3)
    float2* outp = (float2*)d_out;               // 20000 x 128 float2 = out buffer

    char* p = (char*)d_ws;
    unsigned* hp  = (unsigned*)p; p += (size_t)N_NODES * DH * 4;   // 10.24 MB
    unsigned* s1p = (unsigned*)p; p += (size_t)N_NODES * DH * 4;   // 10.24 MB
    unsigned* s2p = (unsigned*)p; p += (size_t)N_NODES * DH * 4;   // 10.24 MB
    int* row_ptr  = (int*)p;      p += ((size_t)N_ADJ * RP * 4 + 15) / 16 * 16;
    int* cnt      = (int*)p;      p += (size_t)N_ADJ * N_NODES * 4;
    int* work     = (int*)p;      p += (size_t)N_ADJ * N_NODES * 4;
    int2* csr     = (int2*)p;                                       // 10.24 MB

    hipMemsetAsync(cnt, 0, (size_t)N_ADJ * N_NODES * sizeof(int), stream);

    dim3 egrid((N_EDGES + 255) / 256, N_ADJ);
    hist_kernel<<<egrid, 256, 0, stream>>>(rows, cnt);
    scan_kernel<<<N_ADJ, 1024, 0, stream>>>(cnt, row_ptr, work);
    scatter_kernel<<<egrid, 256, 0, stream>>>(rows, cols, vals, work, csr);

    matmul_kernel<<<N_NODES / 16, 256, 0, stream>>>(x, W, b, hp);

    stage1_kernel<<<N_NODES / 2, 256, 0, stream>>>(hp, row_ptr, csr, wseq0, wres0,
                                                   wres1, s1p, s2p, outp);
    stage2_kernel<<<N_NODES / 2, 256, 0, stream>>>(s1p, row_ptr, csr, wseq0, wres1,
                                                   s2p, outp);
    stage3_kernel<<<N_NODES / 2, 256, 0, stream>>>(s2p, row_ptr, csr, wseq1, outp);
}

// Round 3
// 532.006 us; speedup vs baseline: 1.5391x; 1.1356x over previous
//
#include <hip/hip_runtime.h>
#include <hip/hip_bf16.h>

#define N_NODES 20000
#define N_EDGES 320000
#define N_ADJ   4
#define D       256
#define DH      128              // packed bf16x2 dwords per feature row
#define RP      (N_NODES + 1)    // row_ptr stride per adjacency

typedef __attribute__((ext_vector_type(8))) short bf8;   // 8 bf16 (4 VGPRs)
typedef __attribute__((ext_vector_type(4))) float f4;    // MFMA accumulator

// ---------------------------------------------------------------------------
// bf16 pack/unpack helpers (RNE rounding; values are finite)
// ---------------------------------------------------------------------------

__device__ __forceinline__ unsigned f2bf_bits(float x) {
    unsigned u = __float_as_uint(x);
    return (u + 0x7FFFu + ((u >> 16) & 1u)) >> 16;
}
__device__ __forceinline__ unsigned pack_bf2(float lo, float hi) {
    return f2bf_bits(lo) | (f2bf_bits(hi) << 16);
}
__device__ __forceinline__ float bf_lo(unsigned p) { return __uint_as_float(p << 16); }
__device__ __forceinline__ float bf_hi(unsigned p) { return __uint_as_float(p & 0xFFFF0000u); }

// ---------------------------------------------------------------------------
// CSR build: histogram -> exclusive scan -> scatter
// ---------------------------------------------------------------------------

__global__ __launch_bounds__(256) void hist_kernel(const int* __restrict__ rows,
                                                   int* __restrict__ cnt) {
    int e = blockIdx.x * 256 + threadIdx.x;
    int a = blockIdx.y;
    if (e < N_EDGES) {
        atomicAdd(&cnt[a * N_NODES + rows[a * N_EDGES + e]], 1);
    }
}

// 1024 threads, shuffle-based wave scans; 2 barriers per 1024-chunk.
__global__ __launch_bounds__(1024) void scan_kernel(const int* __restrict__ cnt,
                                                    int* __restrict__ row_ptr,
                                                    int* __restrict__ work) {
    int a = blockIdx.x, t = threadIdx.x;
    int lane = t & 63, w = t >> 6;            // 16 waves
    __shared__ int wsum[16];
    int carry = 0;
    for (int base = 0; base < N_NODES; base += 1024) {
        int i = base + t;
        int v = (i < N_NODES) ? cnt[a * N_NODES + i] : 0;
        int s = v;                            // inclusive wave scan
        #pragma unroll
        for (int off = 1; off < 64; off <<= 1) {
            int u = __shfl_up(s, off, 64);
            if (lane >= off) s += u;
        }
        if (lane == 63) wsum[w] = s;
        __syncthreads();
        int woff = 0, total = 0;
        #pragma unroll
        for (int j = 0; j < 16; ++j) {        // LDS broadcast reads, no conflicts
            int ws = wsum[j];
            woff  += (j < w) ? ws : 0;
            total += ws;
        }
        __syncthreads();                      // protect wsum before next chunk
        if (i < N_NODES) {
            int val = carry + woff + s - v;   // exclusive
            row_ptr[a * RP + i]   = val;
            work[a * N_NODES + i] = val;
        }
        carry += total;
    }
    if (t == 0) row_ptr[a * RP + N_NODES] = carry;
}

__global__ __launch_bounds__(256) void scatter_kernel(const int* __restrict__ rows,
                                                      const int* __restrict__ cols,
                                                      const float* __restrict__ vals,
                                                      int* __restrict__ work,
                                                      int2* __restrict__ csr) {
    int e = blockIdx.x * 256 + threadIdx.x;
    int a = blockIdx.y;
    if (e < N_EDGES) {
        int r = rows[a * N_EDGES + e];
        int idx = atomicAdd(&work[a * N_NODES + r], 1);
        csr[(size_t)a * N_EDGES + idx] =
            make_int2(cols[a * N_EDGES + e], __float_as_int(vals[a * N_EDGES + e]));
    }
}

// ---------------------------------------------------------------------------
// W -> fragment-ordered bf16 hi/lo tables.  One uint4 (8 bf16) per lane per
// (ks,n) tile, so the matmul's B-fragment load is a single dwordx4.
// B fragment layout (16x16x32): n_idx = lane&15, k = ks*32 + (lane>>4)*8 + j.
// ---------------------------------------------------------------------------

__global__ __launch_bounds__(256) void wfrag_kernel(const float* __restrict__ W,
                                                    uint4* __restrict__ wh,
                                                    uint4* __restrict__ wl) {
    int g = blockIdx.x * 256 + threadIdx.x;   // 0..8191 = (ks*16+n)*64 + lane
    int lane = g & 63;
    int tile = g >> 6;                        // ks*16 + n
    int ks = tile >> 4, n = tile & 15;
    int m = lane & 15, quad = lane >> 4;
    int col = n * 16 + m;
    int k0  = ks * 32 + quad * 8;
    unsigned hbits[8], lbits[8];
    #pragma unroll
    for (int j = 0; j < 8; ++j) {
        float v = W[(k0 + j) * D + col];
        unsigned hb = f2bf_bits(v);
        float lo = v - __uint_as_float(hb << 16);
        hbits[j] = hb;
        lbits[j] = f2bf_bits(lo);
    }
    uint4 hh, ll;
    hh.x = hbits[0] | (hbits[1] << 16); hh.y = hbits[2] | (hbits[3] << 16);
    hh.z = hbits[4] | (hbits[5] << 16); hh.w = hbits[6] | (hbits[7] << 16);
    ll.x = lbits[0] | (lbits[1] << 16); ll.y = lbits[2] | (lbits[3] << 16);
    ll.z = lbits[4] | (lbits[5] << 16); ll.w = lbits[6] | (lbits[7] << 16);
    wh[g] = hh;
    wl[g] = ll;
}

// ---------------------------------------------------------------------------
// h = x @ W + b via bf16 MFMA with hi/lo error compensation (f32-accurate):
//   x@W ~= xh@Wh + xl@Wh + xh@Wl   (dropped xl@Wl term ~ 2^-16 relative)
// One wave per 16-row tile.  A frag: m=lane&15, k=(lane>>4)*8+j.
// C/D frag: col=lane&15, row=(lane>>4)*4+reg.  Output packed bf16x2.
// ---------------------------------------------------------------------------

__global__ __launch_bounds__(256) void mfma_matmul_kernel(const float* __restrict__ x,
                                                          const uint4* __restrict__ wh,
                                                          const uint4* __restrict__ wl,
                                                          const float* __restrict__ b,
                                                          unsigned* __restrict__ hp) {
    int wid = threadIdx.x >> 6, lane = threadIdx.x & 63;
    int r0 = (blockIdx.x * 4 + wid) * 16;
    if (r0 >= N_NODES) return;
    int m = lane & 15, quad = lane >> 4;

    // Preload A fragments (hi/lo) for all 8 k-steps: x tile read once.
    const float* xr = x + (size_t)(r0 + m) * D + quad * 8;
    bf8 ah[8], al[8];
    #pragma unroll
    for (int ks = 0; ks < 8; ++ks) {
        float4 v0 = *(const float4*)(xr + ks * 32);
        float4 v1 = *(const float4*)(xr + ks * 32 + 4);
        float xs[8] = {v0.x, v0.y, v0.z, v0.w, v1.x, v1.y, v1.z, v1.w};
        #pragma unroll
        for (int j = 0; j < 8; ++j) {
            unsigned hb = f2bf_bits(xs[j]);
            float lo = xs[j] - __uint_as_float(hb << 16);
            ah[ks][j] = (short)hb;
            al[ks][j] = (short)f2bf_bits(lo);
        }
    }

    for (int n = 0; n < 16; ++n) {
        f4 c = {0.f, 0.f, 0.f, 0.f};
        #pragma unroll
        for (int ks = 0; ks < 8; ++ks) {
            uint4 bh4 = wh[(ks * 16 + n) * 64 + lane];
            uint4 bl4 = wl[(ks * 16 + n) * 64 + lane];
            bf8 bh = *(bf8*)&bh4;
            bf8 bl = *(bf8*)&bl4;
            c = __builtin_amdgcn_mfma_f32_16x16x32_bf16(ah[ks], bh, c, 0, 0, 0);
            c = __builtin_amdgcn_mfma_f32_16x16x32_bf16(al[ks], bh, c, 0, 0, 0);
            c = __builtin_amdgcn_mfma_f32_16x16x32_bf16(ah[ks], bl, c, 0, 0, 0);
        }
        int col = n * 16 + m;
        float bb = b[col];
        #pragma unroll
        for (int reg = 0; reg < 4; ++reg) {
            float v = c[reg] + bb;            // value at (r0+quad*4+reg, col)
            float o = __shfl_xor(v, 1, 64);   // partner column col^1
            if ((m & 1) == 0) {
                hp[(r0 + quad * 4 + reg) * DH + (col >> 1)] = pack_bf2(v, o);
            }
        }
    }
}

// ---------------------------------------------------------------------------
// Gather one row's segment of one adjacency from a packed-bf16 feature table.
// Thread tt in [0,128) owns features (2tt, 2tt+1).  Unrolled x4 for MLP.
// ---------------------------------------------------------------------------

__device__ __forceinline__ void gather_row2(const int2* __restrict__ E,
                                            int beg, int end,
                                            const unsigned* __restrict__ feat,
                                            int tt, float& r0, float& r1) {
    float s0 = 0.f, s1 = 0.f;
    int e = beg;
    for (; e + 4 <= end; e += 4) {
        int2 c0 = E[e], c1 = E[e + 1], c2 = E[e + 2], c3 = E[e + 3];
        unsigned p0 = feat[c0.x * DH + tt];
        unsigned p1 = feat[c1.x * DH + tt];
        unsigned p2 = feat[c2.x * DH + tt];
        unsigned p3 = feat[c3.x * DH + tt];
        float v0 = __int_as_float(c0.y), v1 = __int_as_float(c1.y);
        float v2 = __int_as_float(c2.y), v3 = __int_as_float(c3.y);
        s0 += v0 * bf_lo(p0); s1 += v0 * bf_hi(p0);
        s0 += v1 * bf_lo(p1); s1 += v1 * bf_hi(p1);
        s0 += v2 * bf_lo(p2); s1 += v2 * bf_hi(p2);
        s0 += v3 * bf_lo(p3); s1 += v3 * bf_hi(p3);
    }
    for (; e < end; ++e) {
        int2 c = E[e];
        unsigned p = feat[c.x * DH + tt];
        float v = __int_as_float(c.y);
        s0 += v * bf_lo(p); s1 += v * bf_hi(p);
    }
    r0 = s0; r1 = s1;
}

// ---------------------------------------------------------------------------
// Stage 1: input h (packed).  Emits s1, s2-partial (packed) and out-partial
// (f32, into d_out).  2 rows per block; waves 0-1 -> row 2b, waves 2-3 -> 2b+1.
// ---------------------------------------------------------------------------

__global__ __launch_bounds__(256) void stage1_kernel(const unsigned* __restrict__ hp,
                                                     const int* __restrict__ row_ptr,
                                                     const int2* __restrict__ csr,
                                                     const float* __restrict__ wseq0,
                                                     const float* __restrict__ wres0,
                                                     const float* __restrict__ wres1,
                                                     unsigned* __restrict__ s1p,
                                                     unsigned* __restrict__ s2p,
                                                     float2* __restrict__ outp) {
    int t = threadIdx.x, tt = t & 127;
    int r = blockIdx.x * 2 + (t >> 7);
    float a0[N_ADJ], a1[N_ADJ];
    #pragma unroll
    for (int a = 0; a < N_ADJ; ++a) {
        int beg = row_ptr[a * RP + r];
        int end = row_ptr[a * RP + r + 1];
        gather_row2(csr + (size_t)a * N_EDGES, beg, end, hp, tt, a0[a], a1[a]);
    }
    const float third = 1.f / 3.f;
    float s1v0 = (wseq0[0] * a0[0] + wseq0[1] * a0[1] + wseq0[2] * a0[2]) * third;
    float s1v1 = (wseq0[0] * a1[0] + wseq0[1] * a1[1] + wseq0[2] * a1[2]) * third;
    float s2v0 = (wres0[0] * a0[0] + wres0[1] * a0[1] + wres0[2] * a0[2] + wres0[3] * a0[3]) * 0.25f;
    float s2v1 = (wres0[0] * a1[0] + wres0[1] * a1[1] + wres0[2] * a1[2] + wres0[3] * a1[3]) * 0.25f;
    float ov0  = (wres1[0] * a0[0] + wres1[1] * a0[1] + wres1[2] * a0[3]) * third;
    float ov1  = (wres1[0] * a1[0] + wres1[1] * a1[1] + wres1[2] * a1[3]) * third;
    int o = r * DH + tt;
    s1p[o]  = pack_bf2(s1v0, s1v1);
    s2p[o]  = pack_bf2(s2v0, s2v1);
    outp[o] = make_float2(ov0, ov1);
}

// ---------------------------------------------------------------------------
// Stage 2: input s1 (packed).  s2 += seq-combo; out-partial += res-combo.
// ---------------------------------------------------------------------------

__global__ __launch_bounds__(256) void stage2_kernel(const unsigned* __restrict__ s1p,
                                                     const int* __restrict__ row_ptr,
                                                     const int2* __restrict__ csr,
                                                     const float* __restrict__ wseq0,
                                                     const float* __restrict__ wres1,
                                                     unsigned* __restrict__ s2p,
                                                     float2* __restrict__ outp) {
    int t = threadIdx.x, tt = t & 127;
    int r = blockIdx.x * 2 + (t >> 7);
    float a0[N_ADJ], a1[N_ADJ];
    #pragma unroll
    for (int a = 0; a < N_ADJ; ++a) {
        int beg = row_ptr[a * RP + r];
        int end = row_ptr[a * RP + r + 1];
        gather_row2(csr + (size_t)a * N_EDGES, beg, end, s1p, tt, a0[a], a1[a]);
    }
    const float third = 1.f / 3.f;
    int o = r * DH + tt;
    unsigned sp = s2p[o];
    float c0 = bf_lo(sp) + (wseq0[3] * a0[0] + wseq0[4] * a0[1] + wseq0[5] * a0[2]) * third;
    float c1 = bf_hi(sp) + (wseq0[3] * a1[0] + wseq0[4] * a1[1] + wseq0[5] * a1[2]) * third;
    s2p[o] = pack_bf2(c0, c1);
    float2 op = outp[o];
    op.x += (wres1[3] * a0[0] + wres1[4] * a0[1] + wres1[5] * a0[3]) * third;
    op.y += (wres1[3] * a1[0] + wres1[4] * a1[1] + wres1[5] * a1[3]) * third;
    outp[o] = op;
}

// ---------------------------------------------------------------------------
// Stage 3: input s2 (adjacencies 0,1), add out-partial, LayerNorm, exact GELU.
// Per-row reduction runs over the row's 2 waves only.
// ---------------------------------------------------------------------------

__global__ __launch_bounds__(256) void stage3_kernel(const unsigned* __restrict__ s2p,
                                                     const int* __restrict__ row_ptr,
                                                     const int2* __restrict__ csr,
                                                     const float* __restrict__ wseq1,
                                                     float2* __restrict__ outp) {
    int t = threadIdx.x, tt = t & 127, half = t >> 7;
    int r = blockIdx.x * 2 + half;
    float a0[2], a1[2];
    #pragma unroll
    for (int a = 0; a < 2; ++a) {
        int beg = row_ptr[a * RP + r];
        int end = row_ptr[a * RP + r + 1];
        gather_row2(csr + (size_t)a * N_EDGES, beg, end, s2p, tt, a0[a], a1[a]);
    }
    int o = r * DH + tt;
    float2 op = outp[o];
    float val0 = op.x + (wseq1[0] * a0[0] + wseq1[1] * a0[1]) * 0.5f;
    float val1 = op.y + (wseq1[0] * a1[0] + wseq1[1] * a1[1]) * 0.5f;

    // LayerNorm over 256 features = 2 values x 128 threads (2 waves per row)
    float v = val0 + val1, v2 = val0 * val0 + val1 * val1;
    #pragma unroll
    for (int off = 32; off > 0; off >>= 1) {
        v  += __shfl_down(v, off, 64);
        v2 += __shfl_down(v2, off, 64);
    }
    __shared__ float sA[4], sB[4];
    int w = t >> 6, lane = t & 63;
    if (lane == 0) { sA[w] = v; sB[w] = v2; }
    __syncthreads();
    float sum  = sA[half * 2] + sA[half * 2 + 1];
    float sum2 = sB[half * 2] + sB[half * 2 + 1];
    float mu   = sum * (1.f / 256.f);
    float var  = sum2 * (1.f / 256.f) - mu * mu;
    float rstd = rsqrtf(var + 1e-5f);
    float y0   = (val0 - mu) * rstd;
    float y1   = (val1 - mu) * rstd;
    float g0 = 0.5f * y0 * (1.f + erff(y0 * 0.70710678118654752440f));
    float g1 = 0.5f * y1 * (1.f + erff(y1 * 0.70710678118654752440f));
    outp[o] = make_float2(g0, g1);
}

// ---------------------------------------------------------------------------

extern "C" void kernel_launch(void* const* d_in, const int* in_sizes, int n_in,
                              void* d_out, int out_size, void* d_ws, size_t ws_size,
                              hipStream_t stream) {
    const float* x     = (const float*)d_in[0];
    const int*   rows  = (const int*)d_in[1];
    const int*   cols  = (const int*)d_in[2];
    const float* vals  = (const float*)d_in[3];
    const float* W     = (const float*)d_in[4];
    const float* b     = (const float*)d_in[5];
    const float* wseq0 = (const float*)d_in[6];  // (2,3)
    const float* wseq1 = (const float*)d_in[7];  // (2,)
    const float* wres0 = (const float*)d_in[8];  // (1,4)
    const float* wres1 = (const float*)d_in[9];  // (2,3)
    float2* outp = (float2*)d_out;               // 20000 x 128 float2 = out buffer

    char* p = (char*)d_ws;
    unsigned* hp  = (unsigned*)p; p += (size_t)N_NODES * DH * 4;   // 10.24 MB
    unsigned* s1p = (unsigned*)p; p += (size_t)N_NODES * DH * 4;   // 10.24 MB
    unsigned* s2p = (unsigned*)p; p += (size_t)N_NODES * DH * 4;   // 10.24 MB
    int* row_ptr  = (int*)p;      p += ((size_t)N_ADJ * RP * 4 + 15) / 16 * 16;
    int* cnt      = (int*)p;      p += (size_t)N_ADJ * N_NODES * 4;
    int* work     = (int*)p;      p += (size_t)N_ADJ * N_NODES * 4;
    uint4* wh     = (uint4*)p;    p += 8192 * 16;                   // 128 KB
    uint4* wl     = (uint4*)p;    p += 8192 * 16;                   // 128 KB
    int2* csr     = (int2*)p;                                       // 10.24 MB

    hipMemsetAsync(cnt, 0, (size_t)N_ADJ * N_NODES * sizeof(int), stream);

    dim3 egrid((N_EDGES + 255) / 256, N_ADJ);
    hist_kernel<<<egrid, 256, 0, stream>>>(rows, cnt);
    scan_kernel<<<N_ADJ, 1024, 0, stream>>>(cnt, row_ptr, work);
    scatter_kernel<<<egrid, 256, 0, stream>>>(rows, cols, vals, work, csr);

    wfrag_kernel<<<32, 256, 0, stream>>>(W, wh, wl);
    mfma_matmul_kernel<<<313, 256, 0, stream>>>(x, wh, wl, b, hp);

    stage1_kernel<<<N_NODES / 2, 256, 0, stream>>>(hp, row_ptr, csr, wseq0, wres0,
                                                   wres1, s1p, s2p, outp);
    stage2_kernel<<<N_NODES / 2, 256, 0, stream>>>(s1p, row_ptr, csr, wseq0, wres1,
                                                   s2p, outp);
    stage3_kernel<<<N_NODES / 2, 256, 0, stream>>>(s2p, row_ptr, csr, wseq1, outp);
}